// Round 1
// baseline (274.353 us; speedup 1.0000x reference)
//
#include <hip/hip_runtime.h>
#include <stdint.h>

// Problem constants
#define B_   2
#define S_   2048
#define D_   768
#define H_   12
#define DH_  64
#define N3_  2304   // 3*D
#define M_   4096   // B*S

typedef __attribute__((ext_vector_type(8))) short   bf16x8;
typedef __attribute__((ext_vector_type(4))) float   f32x4;
typedef __attribute__((ext_vector_type(4))) int     i32x4;
typedef __attribute__((ext_vector_type(4))) unsigned short u16x4;

__device__ inline unsigned short f2bf(float f) {
    union { float f; unsigned u; } v; v.f = f;
    unsigned r = v.u + 0x7FFFu + ((v.u >> 16) & 1u);   // RNE
    return (unsigned short)(r >> 16);
}

// ---------------------------------------------------------------------------
// Prep: fp32 -> bf16 elementwise (vectorized x4)
__global__ void cvt_bf16(const float* __restrict__ in, unsigned short* __restrict__ out, int n4) {
    int i = blockIdx.x * blockDim.x + threadIdx.x;
    if (i >= n4) return;
    f32x4 v = *(const f32x4*)(in + (size_t)i * 4);
    u16x4 o;
    o.x = f2bf(v.x); o.y = f2bf(v.y); o.z = f2bf(v.z); o.w = f2bf(v.w);
    *(u16x4*)(out + (size_t)i * 4) = o;
}

// Prep: transpose fp32 [R][C] -> bf16 [C][R]
__global__ void transpose_bf16(const float* __restrict__ in, unsigned short* __restrict__ out,
                               int R, int C) {
    int id = blockIdx.x * blockDim.x + threadIdx.x;
    if (id >= R * C) return;
    int c = id / R;
    int r = id - c * R;
    out[id] = f2bf(in[(size_t)r * C + c]);
}

// ---------------------------------------------------------------------------
// bf16 MFMA GEMM: C[M][N] = A[M][K] * Bt[N][K]^T + bias
// MODE 0: epilogue scatters bf16 into Q/K/V [B][H][S][dh] (Cout = QKV base)
// MODE 1: epilogue writes fp32 C row-major to Cout
// 128x128 tile, BK=32, 256 threads (4 waves in 2x2), single-buffered LDS.
template <int MODE>
__global__ __launch_bounds__(256) void gemm_bf16(
    const unsigned short* __restrict__ A,
    const unsigned short* __restrict__ Bt,
    const float* __restrict__ bias,
    void* __restrict__ Cout,
    int M, int N, int K)
{
    // stride 40 shorts (80B, 16B-aligned) -> ds_read_b128 lands 2-way max
    __shared__ __align__(16) short Al[128 * 40];
    __shared__ __align__(16) short Bl[128 * 40];

    const int tid  = threadIdx.x;
    const int w    = tid >> 6;
    const int lane = tid & 63;
    const int r    = lane & 15;
    const int quad = lane >> 4;
    const int m0   = blockIdx.y * 128;
    const int n0   = blockIdx.x * 128;
    const int wm   = (w & 1) * 64;
    const int wn   = (w >> 1) * 64;

    f32x4 acc[4][4];
#pragma unroll
    for (int i = 0; i < 4; i++)
#pragma unroll
        for (int j = 0; j < 4; j++) acc[i][j] = f32x4{0.f, 0.f, 0.f, 0.f};

    for (int k0 = 0; k0 < K; k0 += 32) {
        __syncthreads();   // previous iteration's LDS reads done
#pragma unroll
        for (int p = 0; p < 2; p++) {
            int c   = p * 256 + tid;          // 0..511
            int row = c >> 2;                 // 0..127
            int cc  = c & 3;                  // 0..3 (8-elem chunk)
            *(i32x4*)&Al[row * 40 + cc * 8] =
                *(const i32x4*)&A[(size_t)(m0 + row) * K + k0 + cc * 8];
            *(i32x4*)&Bl[row * 40 + cc * 8] =
                *(const i32x4*)&Bt[(size_t)(n0 + row) * K + k0 + cc * 8];
        }
        __syncthreads();

        bf16x8 af[4], bf[4];
#pragma unroll
        for (int mi = 0; mi < 4; mi++)
            af[mi] = *(const bf16x8*)&Al[(wm + mi * 16 + r) * 40 + quad * 8];
#pragma unroll
        for (int ni = 0; ni < 4; ni++)
            bf[ni] = *(const bf16x8*)&Bl[(wn + ni * 16 + r) * 40 + quad * 8];
#pragma unroll
        for (int mi = 0; mi < 4; mi++)
#pragma unroll
            for (int ni = 0; ni < 4; ni++)
                acc[mi][ni] = __builtin_amdgcn_mfma_f32_16x16x32_bf16(
                    af[mi], bf[ni], acc[mi][ni], 0, 0, 0);
    }

    // Epilogue. C/D layout: col = lane&15 (+16*ni), row = quad*4 + reg (+16*mi)
    if (MODE == 0) {
        unsigned short* Q = (unsigned short*)Cout;   // Q,K,V consecutive
        const size_t one = (size_t)B_ * H_ * S_ * DH_;
#pragma unroll
        for (int ni = 0; ni < 4; ni++) {
            int col  = n0 + wn + ni * 16 + r;        // 0..2303
            float bv = bias[col];
            int part = col / 768;                    // 0=q 1=k 2=v
            int cc   = col - part * 768;
            int h    = cc >> 6;
            int d    = cc & 63;
            unsigned short* dst = Q + (size_t)part * one;
#pragma unroll
            for (int mi = 0; mi < 4; mi++) {
#pragma unroll
                for (int i = 0; i < 4; i++) {
                    int row = m0 + wm + mi * 16 + quad * 4 + i;  // = b*S + s
                    int b   = row >> 11;
                    int s   = row & 2047;
                    dst[(((size_t)(b * H_ + h)) * S_ + s) * DH_ + d] =
                        f2bf(acc[mi][ni][i] + bv);
                }
            }
        }
    } else {
        float* Cf = (float*)Cout;
#pragma unroll
        for (int ni = 0; ni < 4; ni++) {
            int col  = n0 + wn + ni * 16 + r;
            float bv = bias[col];
#pragma unroll
            for (int mi = 0; mi < 4; mi++) {
#pragma unroll
                for (int i = 0; i < 4; i++) {
                    int row = m0 + wm + mi * 16 + quad * 4 + i;
                    Cf[(size_t)row * N + col] = acc[mi][ni][i] + bv;
                }
            }
        }
    }
}

// ---------------------------------------------------------------------------
// Flash attention: grid = B*H*(S/64) blocks, 256 threads (4 waves x 16 q-rows).
// Q,K,V: bf16 [B*H][S][64]. Out: bf16 [B][S][D] (heads merged).
__global__ __launch_bounds__(256) void attn_kernel(
    const unsigned short* __restrict__ Q,
    const unsigned short* __restrict__ Kt,
    const unsigned short* __restrict__ V,
    unsigned short* __restrict__ Out)
{
    __shared__ __align__(16) short Kl[64 * 72];        // K tile [kc][d]
    __shared__ __align__(16) short Vl[64 * 72];        // V^T tile [d][kc]
    __shared__ __align__(16) short Pl[4][16 * 72];     // per-wave P [qr][kc]

    const int tid  = threadIdx.x;
    const int w    = tid >> 6;
    const int lane = tid & 63;
    const int r    = lane & 15;
    const int quad = lane >> 4;
    const int bid  = blockIdx.x;
    const int bh   = bid >> 5;            // 0..23
    const int qb   = bid & 31;
    const int b    = bh / H_;
    const int h    = bh - b * H_;
    const size_t base = (size_t)bh * S_ * DH_;
    const int q0   = qb * 64;

    // Q fragments for this wave's 16 rows (A-operand: A[m=r][k=quad*8+j])
    bf16x8 qf[2];
    {
        int qrow = q0 + w * 16 + r;
        qf[0] = *(const bf16x8*)&Q[base + (size_t)qrow * DH_ + quad * 8];
        qf[1] = *(const bf16x8*)&Q[base + (size_t)qrow * DH_ + 32 + quad * 8];
    }

    f32x4 o[4];
#pragma unroll
    for (int nb = 0; nb < 4; nb++) o[nb] = f32x4{0.f, 0.f, 0.f, 0.f};
    float m2[4] = {-__builtin_inff(), -__builtin_inff(), -__builtin_inff(), -__builtin_inff()};
    float lsum[4] = {0.f, 0.f, 0.f, 0.f};
    const float SC = 0.125f * 1.44269504088896340736f;  // (1/sqrt(64)) * log2(e)

    for (int kt = 0; kt < 32; kt++) {
        const int k0 = kt * 64;
        __syncthreads();
        // stage K (natural) and V (transposed) tiles
#pragma unroll
        for (int p = 0; p < 2; p++) {
            int c   = p * 256 + tid;       // 0..511
            int row = c >> 3;              // key index 0..63
            int cc  = c & 7;               // d-chunk 0..7
            *(i32x4*)&Kl[row * 72 + cc * 8] =
                *(const i32x4*)&Kt[base + (size_t)(k0 + row) * DH_ + cc * 8];
            i32x4 vv = *(const i32x4*)&V[base + (size_t)(k0 + row) * DH_ + cc * 8];
            const short* vs = (const short*)&vv;
#pragma unroll
            for (int j = 0; j < 8; j++) Vl[(cc * 8 + j) * 72 + row] = vs[j];
        }
        __syncthreads();

        // scores: S = Q K^T   (B-operand b[j] = K[col][t*32+quad*8+j])
        f32x4 sa[4];
#pragma unroll
        for (int nb = 0; nb < 4; nb++) sa[nb] = f32x4{0.f, 0.f, 0.f, 0.f};
#pragma unroll
        for (int nb = 0; nb < 4; nb++)
#pragma unroll
            for (int t = 0; t < 2; t++) {
                bf16x8 kf = *(const bf16x8*)&Kl[(nb * 16 + r) * 72 + t * 32 + quad * 8];
                sa[nb] = __builtin_amdgcn_mfma_f32_16x16x32_bf16(qf[t], kf, sa[nb], 0, 0, 0);
            }

        // online softmax (exp2 domain), rows = quad*4+i, cols across 16 lanes
        float pv[4][4];
#pragma unroll
        for (int i = 0; i < 4; i++) {
            float s0 = sa[0][i] * SC, s1 = sa[1][i] * SC;
            float s2 = sa[2][i] * SC, s3 = sa[3][i] * SC;
            float tm = fmaxf(fmaxf(s0, s1), fmaxf(s2, s3));
            tm = fmaxf(tm, __shfl_xor(tm, 1));
            tm = fmaxf(tm, __shfl_xor(tm, 2));
            tm = fmaxf(tm, __shfl_xor(tm, 4));
            tm = fmaxf(tm, __shfl_xor(tm, 8));
            float mn = fmaxf(m2[i], tm);
            float p0 = exp2f(s0 - mn), p1 = exp2f(s1 - mn);
            float p2 = exp2f(s2 - mn), p3 = exp2f(s3 - mn);
            float rs = p0 + p1 + p2 + p3;
            rs += __shfl_xor(rs, 1);
            rs += __shfl_xor(rs, 2);
            rs += __shfl_xor(rs, 4);
            rs += __shfl_xor(rs, 8);
            float al = exp2f(m2[i] - mn);
            lsum[i] = lsum[i] * al + rs;
            m2[i] = mn;
#pragma unroll
            for (int nb = 0; nb < 4; nb++) o[nb][i] *= al;
            pv[0][i] = p0; pv[1][i] = p1; pv[2][i] = p2; pv[3][i] = p3;
        }

        // P: C-layout -> LDS -> A-operand layout (same-wave, DS pipe is in-order)
#pragma unroll
        for (int nb = 0; nb < 4; nb++)
#pragma unroll
            for (int i = 0; i < 4; i++)
                Pl[w][(quad * 4 + i) * 72 + nb * 16 + r] = (short)f2bf(pv[nb][i]);

        bf16x8 ap0 = *(const bf16x8*)&Pl[w][r * 72 + quad * 8];
        bf16x8 ap1 = *(const bf16x8*)&Pl[w][r * 72 + 32 + quad * 8];
#pragma unroll
        for (int nb = 0; nb < 4; nb++) {
            bf16x8 v0 = *(const bf16x8*)&Vl[(nb * 16 + r) * 72 + quad * 8];
            bf16x8 v1 = *(const bf16x8*)&Vl[(nb * 16 + r) * 72 + 32 + quad * 8];
            o[nb] = __builtin_amdgcn_mfma_f32_16x16x32_bf16(ap0, v0, o[nb], 0, 0, 0);
            o[nb] = __builtin_amdgcn_mfma_f32_16x16x32_bf16(ap1, v1, o[nb], 0, 0, 0);
        }
    }

    // epilogue: O/l, write bf16 [B][S][D] with heads merged
#pragma unroll
    for (int i = 0; i < 4; i++) {
        float inv = 1.0f / lsum[i];
        int s = q0 + w * 16 + quad * 4 + i;
        size_t ob = ((size_t)b * S_ + s) * D_ + h * DH_;
#pragma unroll
        for (int nb = 0; nb < 4; nb++)
            Out[ob + nb * 16 + r] = f2bf(o[nb][i] * inv);
    }
}

// ---------------------------------------------------------------------------
extern "C" void kernel_launch(void* const* d_in, const int* in_sizes, int n_in,
                              void* d_out, int out_size, void* d_ws, size_t ws_size,
                              hipStream_t stream) {
    const float* x     = (const float*)d_in[0];
    const float* w_in  = (const float*)d_in[1];
    const float* b_in  = (const float*)d_in[2];
    const float* w_out = (const float*)d_in[3];
    const float* b_out = (const float*)d_in[4];
    float* out = (float*)d_out;
    char* ws = (char*)d_ws;

    // workspace layout (bytes)
    unsigned short* xb    = (unsigned short*)(ws);              // 4096x768 bf16   (6291456 B)
    unsigned short* winT  = (unsigned short*)(ws + 6291456);    // 2304x768 bf16   (3538944 B)
    unsigned short* woutT = (unsigned short*)(ws + 9830400);    // 768x768 bf16    (1179648 B)
    unsigned short* QKV   = (unsigned short*)(ws + 11010048);   // 3 x [24][2048][64] bf16
    unsigned short* attn  = (unsigned short*)(ws + 29884416);   // 4096x768 bf16

    cvt_bf16<<<3072, 256, 0, stream>>>(x, xb, (M_ * D_) / 4);
    transpose_bf16<<<(D_ * N3_ + 255) / 256, 256, 0, stream>>>(w_in, winT, D_, N3_);
    transpose_bf16<<<(D_ * D_ + 255) / 256, 256, 0, stream>>>(w_out, woutT, D_, D_);

    gemm_bf16<0><<<dim3(N3_ / 128, M_ / 128), 256, 0, stream>>>(
        xb, winT, b_in, (void*)QKV, M_, N3_, D_);

    attn_kernel<<<B_ * H_ * (S_ / 64), 256, 0, stream>>>(
        QKV, QKV + (size_t)B_ * H_ * S_ * DH_, QKV + 2 * (size_t)B_ * H_ * S_ * DH_, attn);

    gemm_bf16<1><<<dim3(D_ / 128, M_ / 128), 256, 0, stream>>>(
        attn, woutT, b_out, (void*)out, M_, D_, D_);
}